// Round 3
// baseline (14185.643 us; speedup 1.0000x reference)
//
#include <hip/hip_runtime.h>
#include <hip/hip_cooperative_groups.h>
#include <math.h>

namespace cg = cooperative_groups;

// Problem dims
#define SSRC 50
#define NBATCH 64
#define EDIM 300
#define HDIM 512
#define G4H 2048
#define VTGT 10000
#define TSTEPS 49
#define LDW_DEC (2 * HDIM + EDIM)   // 1324
#define HS (NBATCH * HDIM)          // 32768

// ---------------------------------------------------------------------------
// Generic tiled fp32 GEMM: C[m][n] = sum_k A[m][k]*B[n][k] + bias[n]
// A row m optionally gathered: row = aidx[m] (embedding fusion).
// 128x128 tile, BK=8, 256 threads, 8x8 per thread.
// Fragments are 2x4 contiguous float4s (tx*4 / 64+tx*4) so a wave's 16 tx
// read 256 contiguous LDS bytes -> 2-way bank aliasing only (free, m136).
// ---------------------------------------------------------------------------
__global__ __launch_bounds__(256)
void gemm_bias_kernel(const float* __restrict__ A, const int* __restrict__ aidx, int lda,
                      const float* __restrict__ B, int ldb,
                      const float* __restrict__ bias,
                      float* __restrict__ C, int ldc,
                      int M, int N, int K)
{
    __shared__ float As[8][128];
    __shared__ float Bs[8][128];
    const int tid = threadIdx.x;
    const int bm = blockIdx.y * 128;
    const int bn = blockIdx.x * 128;
    const int tx = tid & 15;
    const int ty = tid >> 4;

    float acc[8][8];
#pragma unroll
    for (int i = 0; i < 8; ++i)
#pragma unroll
        for (int j = 0; j < 8; ++j) acc[i][j] = 0.f;

    for (int k0 = 0; k0 < K; k0 += 8) {
#pragma unroll
        for (int i = 0; i < 4; ++i) {
            int idx = tid + i * 256;       // 0..1023
            int r  = idx >> 3;             // 0..127
            int kk = idx & 7;
            int gk = k0 + kk;
            float va = 0.f;
            int gm = bm + r;
            if (gm < M && gk < K) {
                long arow = aidx ? (long)aidx[gm] : (long)gm;
                va = A[arow * (long)lda + gk];
            }
            As[kk][r] = va;
            float vb = 0.f;
            int gn = bn + r;
            if (gn < N && gk < K) vb = B[(long)gn * ldb + gk];
            Bs[kk][r] = vb;
        }
        __syncthreads();
#pragma unroll
        for (int kk = 0; kk < 8; ++kk) {
            const float4 a0 = *reinterpret_cast<const float4*>(&As[kk][ty * 4]);
            const float4 a1 = *reinterpret_cast<const float4*>(&As[kk][64 + ty * 4]);
            const float4 b0 = *reinterpret_cast<const float4*>(&Bs[kk][tx * 4]);
            const float4 b1 = *reinterpret_cast<const float4*>(&Bs[kk][64 + tx * 4]);
            const float a[8] = {a0.x, a0.y, a0.z, a0.w, a1.x, a1.y, a1.z, a1.w};
            const float b[8] = {b0.x, b0.y, b0.z, b0.w, b1.x, b1.y, b1.z, b1.w};
#pragma unroll
            for (int i = 0; i < 8; ++i)
#pragma unroll
                for (int j = 0; j < 8; ++j)
                    acc[i][j] = fmaf(a[i], b[j], acc[i][j]);
        }
        __syncthreads();
    }

#pragma unroll
    for (int i = 0; i < 8; ++i) {
        int m = bm + ((i < 4) ? (ty * 4 + i) : (64 + ty * 4 + i - 4));
        if (m >= M) continue;
#pragma unroll
        for (int j = 0; j < 8; ++j) {
            int n = bn + ((j < 4) ? (tx * 4 + j) : (64 + tx * 4 + j - 4));
            if (n >= N) continue;
            float v = acc[i][j];
            if (bias) v += bias[n];
            C[(long)m * ldc + n] = v;
        }
    }
}

// ---------------------------------------------------------------------------
// Persistent bidirectional encoder. Cooperative launch, grid = 256 blocks:
// blocks [0,128) = forward set, [128,256) = backward set. Each block owns 4
// gate-columns k0..k0+3 (16 weight rows of K=512, 32 KB LDS, staged ONCE).
// Per step: thread (n = tid&63, gate p = tid>>6) computes 4 gate dots against
// h_prev (global, ping-pong), pointwise LSTM update, grid-wide sync.
// ---------------------------------------------------------------------------
struct EncP {
    const float* Xf; const float* Xb;     // 50 x 64 x 2048 input contributions
    const float* Wf; const float* Wb;     // Whh, 2048 x 512
    float* st;                            // ping-pong: [hf c f hb cb]x2, 8*HS
    float* out_f; float* out_b;           // out_b stored pre-reversed
};

__global__ __launch_bounds__(256)
void enc_persist(EncP P)
{
    cg::grid_group grid = cg::this_grid();
    __shared__ float Wl[16 * HDIM];       // 32 KB
    __shared__ float gbuf[64 * 16];       // 4 KB
    const int bset = blockIdx.x >> 7;
    const int b = blockIdx.x & 127;
    const int tid = threadIdx.x;
    const int k0 = b * 4;
    const float* W  = bset ? P.Wb : P.Wf;
    const float* X0 = bset ? P.Xb : P.Xf;
    float* outbuf   = bset ? P.out_b : P.out_f;

    // stage 16 weight rows once: row i = kk*4+g holds W[j = g*512 + k0 + kk]
    for (int idx = tid; idx < 16 * HDIM; idx += 256) {
        int i = idx >> 9;
        int l = idx & 511;
        int kk = i >> 2, g = i & 3;
        int j = g * HDIM + k0 + kk;
        Wl[i * HDIM + l] = W[(size_t)j * HDIM + l];
    }
    __syncthreads();

    const int n = tid & 63;
    const int p = tid >> 6;               // gate index
    const float4* w0 = reinterpret_cast<const float4*>(&Wl[(0 * 4 + p) * HDIM]);
    const float4* w1 = reinterpret_cast<const float4*>(&Wl[(1 * 4 + p) * HDIM]);
    const float4* w2 = reinterpret_cast<const float4*>(&Wl[(2 * 4 + p) * HDIM]);
    const float4* w3 = reinterpret_cast<const float4*>(&Wl[(3 * 4 + p) * HDIM]);

    for (int t = 0; t < SSRC; ++t) {
        const int pp = t & 1;
        const float* h_prev = P.st + pp * 4 * HS + bset * 2 * HS;
        float* h_next       = P.st + (pp ^ 1) * 4 * HS + bset * 2 * HS;
        const float* c_prev = h_prev + HS;
        float* c_next       = h_next + HS;
        const int ts = bset ? (SSRC - 1 - t) : t;
        const float* X = X0 + (size_t)ts * NBATCH * G4H;

        const float4 xi = *reinterpret_cast<const float4*>(X + n * G4H + p * HDIM + k0);
        float acc0 = xi.x, acc1 = xi.y, acc2 = xi.z, acc3 = xi.w;
        const float4* a4 = reinterpret_cast<const float4*>(h_prev + n * HDIM);
#pragma unroll 4
        for (int l = 0; l < HDIM / 4; ++l) {
            const float4 av = a4[l];
            const float4 u0 = w0[l], u1 = w1[l], u2 = w2[l], u3 = w3[l];
            acc0 = fmaf(av.x, u0.x, fmaf(av.y, u0.y, fmaf(av.z, u0.z, fmaf(av.w, u0.w, acc0))));
            acc1 = fmaf(av.x, u1.x, fmaf(av.y, u1.y, fmaf(av.z, u1.z, fmaf(av.w, u1.w, acc1))));
            acc2 = fmaf(av.x, u2.x, fmaf(av.y, u2.y, fmaf(av.z, u2.z, fmaf(av.w, u2.w, acc2))));
            acc3 = fmaf(av.x, u3.x, fmaf(av.y, u3.y, fmaf(av.z, u3.z, fmaf(av.w, u3.w, acc3))));
        }
        gbuf[n * 16 + 0 * 4 + p] = acc0;
        gbuf[n * 16 + 1 * 4 + p] = acc1;
        gbuf[n * 16 + 2 * 4 + p] = acc2;
        gbuf[n * 16 + 3 * 4 + p] = acc3;
        __syncthreads();

        {   // pointwise: thread -> (n2, kk)
            const int n2 = tid & 63;
            const int kk = tid >> 6;
            const int k = k0 + kk;
            const float gi = gbuf[n2 * 16 + kk * 4 + 0];
            const float gf = gbuf[n2 * 16 + kk * 4 + 1];
            const float gg = gbuf[n2 * 16 + kk * 4 + 2];
            const float go = gbuf[n2 * 16 + kk * 4 + 3];
            const float cold = c_prev[n2 * HDIM + k];
            const float si = 1.f / (1.f + __expf(-gi));
            const float sf = 1.f / (1.f + __expf(-gf));
            const float so = 1.f / (1.f + __expf(-go));
            const float tg = tanhf(gg);
            const float cn = sf * cold + si * tg;
            const float hn = so * tanhf(cn);
            c_next[n2 * HDIM + k] = cn;
            h_next[n2 * HDIM + k] = hn;
            outbuf[(size_t)ts * HS + n2 * HDIM + k] = hn;
        }
        __threadfence();
        grid.sync();
    }
}

// ---------------------------------------------------------------------------
// Persistent decoder: attention + LSTM, cooperative, grid = 256 blocks.
// LDS: 8 weight rows x 1536 (ctx-part of dec_Wih | dec_Whh) = 48 KB, staged once.
// Per step: phase A (4 blocks per batch row: h·Wh reduce, softmax over 50,
// 256 ctx outputs each), grid sync, phase B (gates + pointwise), grid sync.
// ---------------------------------------------------------------------------
struct DecP {
    const float* Xd;        // 49 x 64 x 2048 (emb contribution + bias)
    const float* Wih;       // 2048 x 1324
    const float* Whh;       // 2048 x 512
    const float* ee;        // 50 x 64, states·We + energy_b
    const float* WhE;       // energy_W[0:512]
    const float* out_f;     // 50 x 64 x 512
    const float* out_b;     // pre-reversed
    float* dst;             // ping-pong: [dh dc]x2, 4*HS
    float* ctx;             // 64 x 1024
    float* Hs;              // 49 x HS
};

__global__ __launch_bounds__(256)
void dec_persist(DecP P)
{
    cg::grid_group grid = cg::this_grid();
    __shared__ float Wl[8 * 1536];        // 48 KB
    __shared__ float gbuf[64 * 8];
    __shared__ float attnw[SSRC];
    __shared__ float red[4];
    const int b = blockIdx.x;
    const int tid = threadIdx.x;
    const int k0 = b * 2;

    // stage 8 weight rows once: row i = kk*4+g, j = g*512 + k0 + kk,
    // cols [0,1024) from Wih (ctx part), [1024,1536) from Whh.
    for (int i = 0; i < 8; ++i) {
        int kk = i >> 2, g = i & 3;
        int j = g * HDIM + k0 + kk;
        for (int l = tid; l < 1536; l += 256) {
            float v = (l < 1024) ? P.Wih[(size_t)j * LDW_DEC + l]
                                 : P.Whh[(size_t)j * HDIM + (l - 1024)];
            Wl[i * 1536 + l] = v;
        }
    }
    __syncthreads();

    const int n = tid & 63;
    const int p = tid >> 6;
    const float4* w0 = reinterpret_cast<const float4*>(&Wl[p * 1536]);
    const float4* w1 = reinterpret_cast<const float4*>(&Wl[(p + 4) * 1536]);
    const int nA = b >> 2;                // phase-A batch row
    const int q  = b & 3;                 // phase-A quarter of ctx row

    for (int t = 0; t < TSTEPS; ++t) {
        const int pp = t & 1;
        const float* h = P.dst + pp * 2 * HS;
        const float* c = h + HS;
        float* h_next  = P.dst + (pp ^ 1) * 2 * HS;
        float* c_next  = h_next + HS;

        // ---- Phase A: attention ----
        {
            float ps = 0.f;
            for (int l = tid; l < HDIM; l += 256)
                ps = fmaf(h[nA * HDIM + l], P.WhE[l], ps);
#pragma unroll
            for (int off = 32; off > 0; off >>= 1) ps += __shfl_down(ps, off);
            if ((tid & 63) == 0) red[tid >> 6] = ps;
            __syncthreads();
            if (tid == 0) {
                const float hdot = red[0] + red[1] + red[2] + red[3];
                float e[SSRC];
                float m = 0.f;
                for (int s = 0; s < SSRC; ++s) {
                    float v = hdot + P.ee[s * NBATCH + nA];
                    v = v > 0.f ? v : 0.f;
                    e[s] = v;
                    m = fmaxf(m, v);
                }
                float sum = 0.f;
                for (int s = 0; s < SSRC; ++s) { float ex = __expf(e[s] - m); e[s] = ex; sum += ex; }
                const float inv = 1.f / sum;
                for (int s = 0; s < SSRC; ++s) attnw[s] = e[s] * inv;
            }
            __syncthreads();
            const int l = q * 256 + tid;  // 0..1023
            const float* src = (l < HDIM) ? (P.out_f + (size_t)nA * HDIM + l)
                                          : (P.out_b + (size_t)nA * HDIM + (l - HDIM));
            float acc = 0.f;
            for (int s = 0; s < SSRC; ++s)
                acc = fmaf(attnw[s], src[(size_t)s * HS], acc);
            P.ctx[nA * 2 * HDIM + l] = acc;
        }
        __threadfence();
        grid.sync();

        // ---- Phase B: LSTM gates + pointwise ----
        {
            const float* X = P.Xd + (size_t)t * NBATCH * G4H;
            float acc0 = X[n * G4H + p * HDIM + k0];
            float acc1 = X[n * G4H + p * HDIM + k0 + 1];
            const float4* c4 = reinterpret_cast<const float4*>(P.ctx + n * 2 * HDIM);
#pragma unroll 4
            for (int l = 0; l < (2 * HDIM) / 4; ++l) {
                const float4 av = c4[l];
                const float4 u = w0[l], v = w1[l];
                acc0 = fmaf(av.x, u.x, fmaf(av.y, u.y, fmaf(av.z, u.z, fmaf(av.w, u.w, acc0))));
                acc1 = fmaf(av.x, v.x, fmaf(av.y, v.y, fmaf(av.z, v.z, fmaf(av.w, v.w, acc1))));
            }
            const float4* a4 = reinterpret_cast<const float4*>(h + n * HDIM);
            const float4* w0h = w0 + 256;   // offset 1024 floats
            const float4* w1h = w1 + 256;
#pragma unroll 4
            for (int l = 0; l < HDIM / 4; ++l) {
                const float4 av = a4[l];
                const float4 u = w0h[l], v = w1h[l];
                acc0 = fmaf(av.x, u.x, fmaf(av.y, u.y, fmaf(av.z, u.z, fmaf(av.w, u.w, acc0))));
                acc1 = fmaf(av.x, v.x, fmaf(av.y, v.y, fmaf(av.z, v.z, fmaf(av.w, v.w, acc1))));
            }
            gbuf[n * 8 + p]     = acc0;
            gbuf[n * 8 + p + 4] = acc1;
            __syncthreads();

            if (tid < 128) {
                const int n2 = tid & 63;
                const int kk = tid >> 6;
                const int k = k0 + kk;
                const float gi = gbuf[n2 * 8 + kk * 4 + 0];
                const float gf = gbuf[n2 * 8 + kk * 4 + 1];
                const float gg = gbuf[n2 * 8 + kk * 4 + 2];
                const float go = gbuf[n2 * 8 + kk * 4 + 3];
                const float cold = c[n2 * HDIM + k];
                const float si = 1.f / (1.f + __expf(-gi));
                const float sf = 1.f / (1.f + __expf(-gf));
                const float so = 1.f / (1.f + __expf(-go));
                const float tg = tanhf(gg);
                const float cn = sf * cold + si * tg;
                const float hn = so * tanhf(cn);
                c_next[n2 * HDIM + k] = cn;
                h_next[n2 * HDIM + k] = hn;
                P.Hs[(size_t)t * HS + n2 * HDIM + k] = hn;
            }
        }
        __threadfence();
        grid.sync();
    }
}

// ---------------------------------------------------------------------------
// Step-invariant attention key term: ee[s][n] = states[s][n]·We + energy_b
// ---------------------------------------------------------------------------
__global__ __launch_bounds__(64)
void ee_kernel(const float* __restrict__ out_f, const float* __restrict__ out_b,
               const float* __restrict__ We, const float* __restrict__ energy_b,
               float* __restrict__ ee)
{
    const int sn = blockIdx.x;
    const int lane = threadIdx.x;
    const float* f = out_f + (long)sn * HDIM;
    const float* bb = out_b + (long)sn * HDIM;
    float p = 0.f;
    for (int l = lane; l < HDIM; l += 64)
        p = fmaf(f[l], We[l], fmaf(bb[l], We[HDIM + l], p));
#pragma unroll
    for (int off = 32; off > 0; off >>= 1) p += __shfl_down(p, off);
    if (lane == 0) ee[sn] = p + energy_b[0];
}

// concat two 64x512 buffers -> 64 x 1024
__global__ __launch_bounds__(256)
void hcat_kernel(const float* __restrict__ a, const float* __restrict__ b,
                 float* __restrict__ cat)
{
    const int n = blockIdx.x;
    for (int l = threadIdx.x; l < 2 * HDIM; l += 256)
        cat[n * 2 * HDIM + l] = (l < HDIM) ? a[n * HDIM + l] : b[n * HDIM + l - HDIM];
}

// ---------------------------------------------------------------------------
extern "C" void kernel_launch(void* const* d_in, const int* in_sizes, int n_in,
                              void* d_out, int out_size, void* d_ws, size_t ws_size,
                              hipStream_t stream)
{
    const int*   source    = (const int*)  d_in[0];
    const int*   target    = (const int*)  d_in[1];
    const float* enc_emb   = (const float*)d_in[2];
    const float* enc_Wih_f = (const float*)d_in[3];
    const float* enc_Whh_f = (const float*)d_in[4];
    const float* enc_b_f   = (const float*)d_in[5];
    const float* enc_Wih_b = (const float*)d_in[6];
    const float* enc_Whh_b = (const float*)d_in[7];
    const float* enc_b_b   = (const float*)d_in[8];
    const float* fc_hid_W  = (const float*)d_in[9];
    const float* fc_hid_b  = (const float*)d_in[10];
    const float* fc_cell_W = (const float*)d_in[11];
    const float* fc_cell_b = (const float*)d_in[12];
    const float* dec_emb   = (const float*)d_in[13];
    const float* dec_Wih   = (const float*)d_in[14];
    const float* dec_Whh   = (const float*)d_in[15];
    const float* dec_b     = (const float*)d_in[16];
    const float* energy_W  = (const float*)d_in[17];
    const float* energy_b  = (const float*)d_in[18];
    const float* fc_W      = (const float*)d_in[19];
    const float* fc_b      = (const float*)d_in[20];
    float* out = (float*)d_out;

    float* w = (float*)d_ws;
    size_t o = 0;
    auto alloc = [&](size_t nf) { float* p = w + o; o += nf; return p; };
    float* Xf    = alloc((size_t)SSRC * NBATCH * G4H);
    float* Xb    = alloc((size_t)SSRC * NBATCH * G4H);
    float* out_f = alloc((size_t)SSRC * HS);
    float* out_b = alloc((size_t)SSRC * HS);             // stored pre-reversed
    float* Hs    = alloc((size_t)TSTEPS * HS);
    float* st    = alloc((size_t)8 * HS);   // [hf cf hb cb] x ping-pong
    float* dst   = alloc((size_t)4 * HS);   // [dh dc] x ping-pong
    float* hcat  = alloc((size_t)NBATCH * 2 * HDIM);
    float* ccat  = alloc((size_t)NBATCH * 2 * HDIM);
    float* ee    = alloc((size_t)SSRC * NBATCH);
    float* ctx   = alloc((size_t)NBATCH * 2 * HDIM);
    float* Xd = Xf;  // alias: encoder input buffer reused after encoder finishes

    // zero initial LSTM states + output step 0
    hipMemsetAsync(st, 0, (size_t)4 * HS * sizeof(float), stream);
    hipMemsetAsync(out, 0, (size_t)NBATCH * VTGT * sizeof(float), stream);

    // encoder input GEMMs (embedding gather fused): X = emb[source] @ Wih.T + b
    {
        dim3 g(G4H / 128, (SSRC * NBATCH + 127) / 128);
        gemm_bias_kernel<<<g, 256, 0, stream>>>(enc_emb, source, EDIM, enc_Wih_f, EDIM,
                                                enc_b_f, Xf, G4H, SSRC * NBATCH, G4H, EDIM);
        gemm_bias_kernel<<<g, 256, 0, stream>>>(enc_emb, source, EDIM, enc_Wih_b, EDIM,
                                                enc_b_b, Xb, G4H, SSRC * NBATCH, G4H, EDIM);
    }

    // persistent bidirectional encoder (50 steps, 1 launch)
    {
        EncP ep;
        ep.Xf = Xf; ep.Xb = Xb; ep.Wf = enc_Whh_f; ep.Wb = enc_Whh_b;
        ep.st = st; ep.out_f = out_f; ep.out_b = out_b;
        void* args[] = { &ep };
        hipLaunchCooperativeKernel((const void*)enc_persist, dim3(256), dim3(256),
                                   args, 0, stream);
    }

    // step-invariant attention key term + decoder init state
    // final states land in ping-pong slot 0 (50 is even): hf=st, cf=st+HS, hb=st+2HS, cb=st+3HS
    ee_kernel<<<SSRC * NBATCH, 64, 0, stream>>>(out_f, out_b, energy_W + HDIM, energy_b, ee);
    hcat_kernel<<<NBATCH, 256, 0, stream>>>(st, st + 2 * HS, hcat);           // h concat
    hcat_kernel<<<NBATCH, 256, 0, stream>>>(st + HS, st + 3 * HS, ccat);      // c concat
    {
        dim3 g(HDIM / 128, 1);
        gemm_bias_kernel<<<g, 256, 0, stream>>>(hcat, nullptr, 2 * HDIM, fc_hid_W, 2 * HDIM,
                                                fc_hid_b, dst, HDIM, NBATCH, HDIM, 2 * HDIM);
        gemm_bias_kernel<<<g, 256, 0, stream>>>(ccat, nullptr, 2 * HDIM, fc_cell_W, 2 * HDIM,
                                                fc_cell_b, dst + HS, HDIM, NBATCH, HDIM, 2 * HDIM);
    }

    // decoder embedding contribution (reuses Xf buffer — safe: encoder done)
    {
        dim3 g(G4H / 128, (TSTEPS * NBATCH + 127) / 128);
        gemm_bias_kernel<<<g, 256, 0, stream>>>(dec_emb, target, EDIM, dec_Wih + 2 * HDIM,
                                                LDW_DEC, dec_b, Xd, G4H,
                                                TSTEPS * NBATCH, G4H, EDIM);
    }

    // persistent decoder (49 steps, 1 launch)
    {
        DecP dp;
        dp.Xd = Xd; dp.Wih = dec_Wih; dp.Whh = dec_Whh; dp.ee = ee;
        dp.WhE = energy_W; dp.out_f = out_f; dp.out_b = out_b;
        dp.dst = dst; dp.ctx = ctx; dp.Hs = Hs;
        void* args[] = { &dp };
        hipLaunchCooperativeKernel((const void*)dec_persist, dim3(256), dim3(256),
                                   args, 0, stream);
    }

    // deferred output projection: preds = Hs @ fc_W.T + fc_b  -> out[1:]
    {
        dim3 g((VTGT + 127) / 128, (TSTEPS * NBATCH + 127) / 128);
        gemm_bias_kernel<<<g, 256, 0, stream>>>(Hs, nullptr, HDIM, fc_W, HDIM, fc_b,
                                                out + (size_t)NBATCH * VTGT, VTGT,
                                                TSTEPS * NBATCH, VTGT, HDIM);
    }
}

// Round 4
// 9504.176 us; speedup vs baseline: 1.4926x; 1.4926x over previous
//
#include <hip/hip_runtime.h>
#include <hip/hip_cooperative_groups.h>
#include <math.h>

// Problem dims
#define SSRC 50
#define NBATCH 64
#define EDIM 300
#define HDIM 512
#define G4H 2048
#define VTGT 10000
#define TSTEPS 49
#define LDW_DEC (2 * HDIM + EDIM)   // 1324
#define HS (NBATCH * HDIM)          // 32768

// ---------------------------------------------------------------------------
// Lightweight grid barrier. Monotonic counter, one ACQ_REL RMW per block
// (release: __syncthreads has already drained all waves' stores to L2; the
// RMW's release part writes back L2 to the coherence point), relaxed spin
// with s_sleep backoff, single acquire fence on exit.
// ---------------------------------------------------------------------------
__device__ __forceinline__ void grid_barrier(unsigned* cnt, unsigned nblocks)
{
    __syncthreads();
    if (threadIdx.x == 0) {
        unsigned old = __hip_atomic_fetch_add(cnt, 1u, __ATOMIC_ACQ_REL,
                                              __HIP_MEMORY_SCOPE_AGENT);
        unsigned target = (old / nblocks + 1u) * nblocks;
        while (__hip_atomic_load(cnt, __ATOMIC_RELAXED,
                                 __HIP_MEMORY_SCOPE_AGENT) < target)
            __builtin_amdgcn_s_sleep(2);
    }
    __syncthreads();
    __builtin_amdgcn_fence(__ATOMIC_ACQUIRE, "agent");
}

// ---------------------------------------------------------------------------
// Generic tiled fp32 GEMM: C[m][n] = sum_k A[m][k]*B[n][k] + bias[n]
// A row m optionally gathered: row = aidx[m] (embedding fusion).
// 128x128 tile, BK=8, 256 threads, 8x8 per thread.
// LDS rows padded to 132 floats (528 B, float4-aligned): staging stores go
// from 8-way bank conflicts (bank=r%32 for all kk) to ~2-way (free, m136).
// ---------------------------------------------------------------------------
__global__ __launch_bounds__(256)
void gemm_bias_kernel(const float* __restrict__ A, const int* __restrict__ aidx, int lda,
                      const float* __restrict__ B, int ldb,
                      const float* __restrict__ bias,
                      float* __restrict__ C, int ldc,
                      int M, int N, int K)
{
    __shared__ float As[8][132];
    __shared__ float Bs[8][132];
    const int tid = threadIdx.x;
    const int bm = blockIdx.y * 128;
    const int bn = blockIdx.x * 128;
    const int tx = tid & 15;
    const int ty = tid >> 4;

    float acc[8][8];
#pragma unroll
    for (int i = 0; i < 8; ++i)
#pragma unroll
        for (int j = 0; j < 8; ++j) acc[i][j] = 0.f;

    for (int k0 = 0; k0 < K; k0 += 8) {
#pragma unroll
        for (int i = 0; i < 4; ++i) {
            int idx = tid + i * 256;       // 0..1023
            int r  = idx >> 3;             // 0..127
            int kk = idx & 7;
            int gk = k0 + kk;
            float va = 0.f;
            int gm = bm + r;
            if (gm < M && gk < K) {
                long arow = aidx ? (long)aidx[gm] : (long)gm;
                va = A[arow * (long)lda + gk];
            }
            As[kk][r] = va;
            float vb = 0.f;
            int gn = bn + r;
            if (gn < N && gk < K) vb = B[(long)gn * ldb + gk];
            Bs[kk][r] = vb;
        }
        __syncthreads();
#pragma unroll
        for (int kk = 0; kk < 8; ++kk) {
            const float4 a0 = *reinterpret_cast<const float4*>(&As[kk][ty * 4]);
            const float4 a1 = *reinterpret_cast<const float4*>(&As[kk][64 + ty * 4]);
            const float4 b0 = *reinterpret_cast<const float4*>(&Bs[kk][tx * 4]);
            const float4 b1 = *reinterpret_cast<const float4*>(&Bs[kk][64 + tx * 4]);
            const float a[8] = {a0.x, a0.y, a0.z, a0.w, a1.x, a1.y, a1.z, a1.w};
            const float b[8] = {b0.x, b0.y, b0.z, b0.w, b1.x, b1.y, b1.z, b1.w};
#pragma unroll
            for (int i = 0; i < 8; ++i)
#pragma unroll
                for (int j = 0; j < 8; ++j)
                    acc[i][j] = fmaf(a[i], b[j], acc[i][j]);
        }
        __syncthreads();
    }

#pragma unroll
    for (int i = 0; i < 8; ++i) {
        int m = bm + ((i < 4) ? (ty * 4 + i) : (64 + ty * 4 + i - 4));
        if (m >= M) continue;
#pragma unroll
        for (int j = 0; j < 8; ++j) {
            int n = bn + ((j < 4) ? (tx * 4 + j) : (64 + tx * 4 + j - 4));
            if (n >= N) continue;
            float v = acc[i][j];
            if (bias) v += bias[n];
            C[(long)m * ldc + n] = v;
        }
    }
}

// ---------------------------------------------------------------------------
// Persistent bidirectional encoder. Cooperative launch, grid = 256 blocks:
// blocks [0,128) = forward set, [128,256) = backward set. Each block owns 4
// gate-columns k0..k0+3 (16 weight rows of K=512, 32 KB LDS, staged ONCE).
// Per step: thread (n = tid&63, gate p = tid>>6) computes 4 gate dots against
// h_prev (global, ping-pong), pointwise LSTM update, grid-wide barrier.
// ---------------------------------------------------------------------------
struct EncP {
    const float* Xf; const float* Xb;     // 50 x 64 x 2048 input contributions
    const float* Wf; const float* Wb;     // Whh, 2048 x 512
    float* st;                            // ping-pong: [hf cf hb cb]x2, 8*HS
    float* out_f; float* out_b;           // out_b stored pre-reversed
    unsigned* bar;
};

__global__ __launch_bounds__(256)
void enc_persist(EncP P)
{
    __shared__ float Wl[16 * HDIM];       // 32 KB
    __shared__ float gbuf[64 * 16];       // 4 KB
    const int bset = blockIdx.x >> 7;
    const int b = blockIdx.x & 127;
    const int tid = threadIdx.x;
    const int k0 = b * 4;
    const float* W  = bset ? P.Wb : P.Wf;
    const float* X0 = bset ? P.Xb : P.Xf;
    float* outbuf   = bset ? P.out_b : P.out_f;

    // stage 16 weight rows once: row i = kk*4+g holds W[j = g*512 + k0 + kk]
    for (int idx = tid; idx < 16 * HDIM; idx += 256) {
        int i = idx >> 9;
        int l = idx & 511;
        int kk = i >> 2, g = i & 3;
        int j = g * HDIM + k0 + kk;
        Wl[i * HDIM + l] = W[(size_t)j * HDIM + l];
    }
    __syncthreads();

    const int n = tid & 63;
    const int p = tid >> 6;               // gate index
    const float4* w0 = reinterpret_cast<const float4*>(&Wl[(0 * 4 + p) * HDIM]);
    const float4* w1 = reinterpret_cast<const float4*>(&Wl[(1 * 4 + p) * HDIM]);
    const float4* w2 = reinterpret_cast<const float4*>(&Wl[(2 * 4 + p) * HDIM]);
    const float4* w3 = reinterpret_cast<const float4*>(&Wl[(3 * 4 + p) * HDIM]);

    for (int t = 0; t < SSRC; ++t) {
        const int pp = t & 1;
        const float* h_prev = P.st + pp * 4 * HS + bset * 2 * HS;
        float* h_next       = P.st + (pp ^ 1) * 4 * HS + bset * 2 * HS;
        const float* c_prev = h_prev + HS;
        float* c_next       = h_next + HS;
        const int ts = bset ? (SSRC - 1 - t) : t;
        const float* X = X0 + (size_t)ts * NBATCH * G4H;

        const float4 xi = *reinterpret_cast<const float4*>(X + n * G4H + p * HDIM + k0);
        float acc0 = xi.x, acc1 = xi.y, acc2 = xi.z, acc3 = xi.w;
        const float4* a4 = reinterpret_cast<const float4*>(h_prev + n * HDIM);
#pragma unroll 4
        for (int l = 0; l < HDIM / 4; ++l) {
            const float4 av = a4[l];
            const float4 u0 = w0[l], u1 = w1[l], u2 = w2[l], u3 = w3[l];
            acc0 = fmaf(av.x, u0.x, fmaf(av.y, u0.y, fmaf(av.z, u0.z, fmaf(av.w, u0.w, acc0))));
            acc1 = fmaf(av.x, u1.x, fmaf(av.y, u1.y, fmaf(av.z, u1.z, fmaf(av.w, u1.w, acc1))));
            acc2 = fmaf(av.x, u2.x, fmaf(av.y, u2.y, fmaf(av.z, u2.z, fmaf(av.w, u2.w, acc2))));
            acc3 = fmaf(av.x, u3.x, fmaf(av.y, u3.y, fmaf(av.z, u3.z, fmaf(av.w, u3.w, acc3))));
        }
        gbuf[n * 16 + 0 * 4 + p] = acc0;
        gbuf[n * 16 + 1 * 4 + p] = acc1;
        gbuf[n * 16 + 2 * 4 + p] = acc2;
        gbuf[n * 16 + 3 * 4 + p] = acc3;
        __syncthreads();

        {   // pointwise: thread -> (n2, kk)
            const int n2 = tid & 63;
            const int kk = tid >> 6;
            const int k = k0 + kk;
            const float gi = gbuf[n2 * 16 + kk * 4 + 0];
            const float gf = gbuf[n2 * 16 + kk * 4 + 1];
            const float gg = gbuf[n2 * 16 + kk * 4 + 2];
            const float go = gbuf[n2 * 16 + kk * 4 + 3];
            const float cold = c_prev[n2 * HDIM + k];
            const float si = 1.f / (1.f + __expf(-gi));
            const float sf = 1.f / (1.f + __expf(-gf));
            const float so = 1.f / (1.f + __expf(-go));
            const float tg = tanhf(gg);
            const float cn = sf * cold + si * tg;
            const float hn = so * tanhf(cn);
            c_next[n2 * HDIM + k] = cn;
            h_next[n2 * HDIM + k] = hn;
            outbuf[(size_t)ts * HS + n2 * HDIM + k] = hn;
        }
        grid_barrier(P.bar, 256u);
    }
}

// ---------------------------------------------------------------------------
// Persistent decoder: attention + LSTM, cooperative, grid = 256 blocks.
// LDS: 8 weight rows x 1536 (ctx-part of dec_Wih | dec_Whh) = 48 KB, staged once.
// Per step: phase A (4 blocks per batch row: h·Wh reduce, softmax over 50,
// 256 ctx outputs each), barrier, phase B (gates + pointwise), barrier.
// ---------------------------------------------------------------------------
struct DecP {
    const float* Xd;        // 49 x 64 x 2048 (emb contribution + bias)
    const float* Wih;       // 2048 x 1324
    const float* Whh;       // 2048 x 512
    const float* ee;        // 50 x 64, states·We + energy_b
    const float* WhE;       // energy_W[0:512]
    const float* out_f;     // 50 x 64 x 512
    const float* out_b;     // pre-reversed
    float* dst;             // ping-pong: [dh dc]x2, 4*HS
    float* ctx;             // 64 x 1024
    float* Hs;              // 49 x HS
    unsigned* bar;
};

__global__ __launch_bounds__(256)
void dec_persist(DecP P)
{
    __shared__ float Wl[8 * 1536];        // 48 KB
    __shared__ float gbuf[64 * 8];
    __shared__ float attnw[SSRC];
    __shared__ float red[4];
    const int b = blockIdx.x;
    const int tid = threadIdx.x;
    const int k0 = b * 2;

    // stage 8 weight rows once: row i = kk*4+g, j = g*512 + k0 + kk,
    // cols [0,1024) from Wih (ctx part), [1024,1536) from Whh.
    for (int i = 0; i < 8; ++i) {
        int kk = i >> 2, g = i & 3;
        int j = g * HDIM + k0 + kk;
        for (int l = tid; l < 1536; l += 256) {
            float v = (l < 1024) ? P.Wih[(size_t)j * LDW_DEC + l]
                                 : P.Whh[(size_t)j * HDIM + (l - 1024)];
            Wl[i * 1536 + l] = v;
        }
    }
    __syncthreads();

    const int n = tid & 63;
    const int p = tid >> 6;
    const float4* w0 = reinterpret_cast<const float4*>(&Wl[p * 1536]);
    const float4* w1 = reinterpret_cast<const float4*>(&Wl[(p + 4) * 1536]);
    const int nA = b >> 2;                // phase-A batch row
    const int q  = b & 3;                 // phase-A quarter of ctx row

    for (int t = 0; t < TSTEPS; ++t) {
        const int pp = t & 1;
        const float* h = P.dst + pp * 2 * HS;
        const float* c = h + HS;
        float* h_next  = P.dst + (pp ^ 1) * 2 * HS;
        float* c_next  = h_next + HS;

        // ---- Phase A: attention ----
        {
            float ps = 0.f;
            for (int l = tid; l < HDIM; l += 256)
                ps = fmaf(h[nA * HDIM + l], P.WhE[l], ps);
#pragma unroll
            for (int off = 32; off > 0; off >>= 1) ps += __shfl_down(ps, off);
            if ((tid & 63) == 0) red[tid >> 6] = ps;
            __syncthreads();
            if (tid == 0) {
                const float hdot = red[0] + red[1] + red[2] + red[3];
                float e[SSRC];
                float m = 0.f;
                for (int s = 0; s < SSRC; ++s) {
                    float v = hdot + P.ee[s * NBATCH + nA];
                    v = v > 0.f ? v : 0.f;
                    e[s] = v;
                    m = fmaxf(m, v);
                }
                float sum = 0.f;
                for (int s = 0; s < SSRC; ++s) { float ex = __expf(e[s] - m); e[s] = ex; sum += ex; }
                const float inv = 1.f / sum;
                for (int s = 0; s < SSRC; ++s) attnw[s] = e[s] * inv;
            }
            __syncthreads();
            const int l = q * 256 + tid;  // 0..1023
            const float* src = (l < HDIM) ? (P.out_f + (size_t)nA * HDIM + l)
                                          : (P.out_b + (size_t)nA * HDIM + (l - HDIM));
            float acc = 0.f;
            for (int s = 0; s < SSRC; ++s)
                acc = fmaf(attnw[s], src[(size_t)s * HS], acc);
            P.ctx[nA * 2 * HDIM + l] = acc;
        }
        grid_barrier(P.bar, 256u);

        // ---- Phase B: LSTM gates + pointwise ----
        {
            const float* X = P.Xd + (size_t)t * NBATCH * G4H;
            float acc0 = X[n * G4H + p * HDIM + k0];
            float acc1 = X[n * G4H + p * HDIM + k0 + 1];
            const float4* c4 = reinterpret_cast<const float4*>(P.ctx + n * 2 * HDIM);
#pragma unroll 4
            for (int l = 0; l < (2 * HDIM) / 4; ++l) {
                const float4 av = c4[l];
                const float4 u = w0[l], v = w1[l];
                acc0 = fmaf(av.x, u.x, fmaf(av.y, u.y, fmaf(av.z, u.z, fmaf(av.w, u.w, acc0))));
                acc1 = fmaf(av.x, v.x, fmaf(av.y, v.y, fmaf(av.z, v.z, fmaf(av.w, v.w, acc1))));
            }
            const float4* a4 = reinterpret_cast<const float4*>(h + n * HDIM);
            const float4* w0h = w0 + 256;   // offset 1024 floats
            const float4* w1h = w1 + 256;
#pragma unroll 4
            for (int l = 0; l < HDIM / 4; ++l) {
                const float4 av = a4[l];
                const float4 u = w0h[l], v = w1h[l];
                acc0 = fmaf(av.x, u.x, fmaf(av.y, u.y, fmaf(av.z, u.z, fmaf(av.w, u.w, acc0))));
                acc1 = fmaf(av.x, v.x, fmaf(av.y, v.y, fmaf(av.z, v.z, fmaf(av.w, v.w, acc1))));
            }
            gbuf[n * 8 + p]     = acc0;
            gbuf[n * 8 + p + 4] = acc1;
            __syncthreads();

            if (tid < 128) {
                const int n2 = tid & 63;
                const int kk = tid >> 6;
                const int k = k0 + kk;
                const float gi = gbuf[n2 * 8 + kk * 4 + 0];
                const float gf = gbuf[n2 * 8 + kk * 4 + 1];
                const float gg = gbuf[n2 * 8 + kk * 4 + 2];
                const float go = gbuf[n2 * 8 + kk * 4 + 3];
                const float cold = c[n2 * HDIM + k];
                const float si = 1.f / (1.f + __expf(-gi));
                const float sf = 1.f / (1.f + __expf(-gf));
                const float so = 1.f / (1.f + __expf(-go));
                const float tg = tanhf(gg);
                const float cn = sf * cold + si * tg;
                const float hn = so * tanhf(cn);
                c_next[n2 * HDIM + k] = cn;
                h_next[n2 * HDIM + k] = hn;
                P.Hs[(size_t)t * HS + n2 * HDIM + k] = hn;
            }
        }
        grid_barrier(P.bar, 256u);
    }
}

// ---------------------------------------------------------------------------
// Step-invariant attention key term: ee[s][n] = states[s][n]·We + energy_b
// ---------------------------------------------------------------------------
__global__ __launch_bounds__(64)
void ee_kernel(const float* __restrict__ out_f, const float* __restrict__ out_b,
               const float* __restrict__ We, const float* __restrict__ energy_b,
               float* __restrict__ ee)
{
    const int sn = blockIdx.x;
    const int lane = threadIdx.x;
    const float* f = out_f + (long)sn * HDIM;
    const float* bb = out_b + (long)sn * HDIM;
    float p = 0.f;
    for (int l = lane; l < HDIM; l += 64)
        p = fmaf(f[l], We[l], fmaf(bb[l], We[HDIM + l], p));
#pragma unroll
    for (int off = 32; off > 0; off >>= 1) p += __shfl_down(p, off);
    if (lane == 0) ee[sn] = p + energy_b[0];
}

// concat two 64x512 buffers -> 64 x 1024
__global__ __launch_bounds__(256)
void hcat_kernel(const float* __restrict__ a, const float* __restrict__ b,
                 float* __restrict__ cat)
{
    const int n = blockIdx.x;
    for (int l = threadIdx.x; l < 2 * HDIM; l += 256)
        cat[n * 2 * HDIM + l] = (l < HDIM) ? a[n * HDIM + l] : b[n * HDIM + l - HDIM];
}

// ---------------------------------------------------------------------------
extern "C" void kernel_launch(void* const* d_in, const int* in_sizes, int n_in,
                              void* d_out, int out_size, void* d_ws, size_t ws_size,
                              hipStream_t stream)
{
    const int*   source    = (const int*)  d_in[0];
    const int*   target    = (const int*)  d_in[1];
    const float* enc_emb   = (const float*)d_in[2];
    const float* enc_Wih_f = (const float*)d_in[3];
    const float* enc_Whh_f = (const float*)d_in[4];
    const float* enc_b_f   = (const float*)d_in[5];
    const float* enc_Wih_b = (const float*)d_in[6];
    const float* enc_Whh_b = (const float*)d_in[7];
    const float* enc_b_b   = (const float*)d_in[8];
    const float* fc_hid_W  = (const float*)d_in[9];
    const float* fc_hid_b  = (const float*)d_in[10];
    const float* fc_cell_W = (const float*)d_in[11];
    const float* fc_cell_b = (const float*)d_in[12];
    const float* dec_emb   = (const float*)d_in[13];
    const float* dec_Wih   = (const float*)d_in[14];
    const float* dec_Whh   = (const float*)d_in[15];
    const float* dec_b     = (const float*)d_in[16];
    const float* energy_W  = (const float*)d_in[17];
    const float* energy_b  = (const float*)d_in[18];
    const float* fc_W      = (const float*)d_in[19];
    const float* fc_b      = (const float*)d_in[20];
    float* out = (float*)d_out;

    float* w = (float*)d_ws;
    size_t o = 0;
    auto alloc = [&](size_t nf) { float* p = w + o; o += nf; return p; };
    float* Xf    = alloc((size_t)SSRC * NBATCH * G4H);
    float* Xb    = alloc((size_t)SSRC * NBATCH * G4H);
    float* out_f = alloc((size_t)SSRC * HS);
    float* out_b = alloc((size_t)SSRC * HS);             // stored pre-reversed
    float* Hs    = alloc((size_t)TSTEPS * HS);
    float* st    = alloc((size_t)8 * HS);   // [hf cf hb cb] x ping-pong
    float* dst   = alloc((size_t)4 * HS);   // [dh dc] x ping-pong
    float* hcat  = alloc((size_t)NBATCH * 2 * HDIM);
    float* ccat  = alloc((size_t)NBATCH * 2 * HDIM);
    float* ee    = alloc((size_t)SSRC * NBATCH);
    float* ctx   = alloc((size_t)NBATCH * 2 * HDIM);
    unsigned* bars = (unsigned*)alloc(16);  // [0]=enc counter, [1]=dec counter
    float* Xd = Xf;  // alias: encoder input buffer reused after encoder finishes

    // zero initial LSTM states, barrier counters, output step 0
    hipMemsetAsync(st, 0, (size_t)4 * HS * sizeof(float), stream);
    hipMemsetAsync(bars, 0, 16 * sizeof(float), stream);
    hipMemsetAsync(out, 0, (size_t)NBATCH * VTGT * sizeof(float), stream);

    // encoder input GEMMs (embedding gather fused): X = emb[source] @ Wih.T + b
    {
        dim3 g(G4H / 128, (SSRC * NBATCH + 127) / 128);
        gemm_bias_kernel<<<g, 256, 0, stream>>>(enc_emb, source, EDIM, enc_Wih_f, EDIM,
                                                enc_b_f, Xf, G4H, SSRC * NBATCH, G4H, EDIM);
        gemm_bias_kernel<<<g, 256, 0, stream>>>(enc_emb, source, EDIM, enc_Wih_b, EDIM,
                                                enc_b_b, Xb, G4H, SSRC * NBATCH, G4H, EDIM);
    }

    // persistent bidirectional encoder (50 steps, 1 launch)
    {
        EncP ep;
        ep.Xf = Xf; ep.Xb = Xb; ep.Wf = enc_Whh_f; ep.Wb = enc_Whh_b;
        ep.st = st; ep.out_f = out_f; ep.out_b = out_b; ep.bar = bars + 0;
        void* args[] = { &ep };
        hipLaunchCooperativeKernel((const void*)enc_persist, dim3(256), dim3(256),
                                   args, 0, stream);
    }

    // step-invariant attention key term + decoder init state
    // final states land in ping-pong slot 0 (50 is even): hf=st, cf=st+HS, hb=st+2HS, cb=st+3HS
    ee_kernel<<<SSRC * NBATCH, 64, 0, stream>>>(out_f, out_b, energy_W + HDIM, energy_b, ee);
    hcat_kernel<<<NBATCH, 256, 0, stream>>>(st, st + 2 * HS, hcat);           // h concat
    hcat_kernel<<<NBATCH, 256, 0, stream>>>(st + HS, st + 3 * HS, ccat);      // c concat
    {
        dim3 g(HDIM / 128, 1);
        gemm_bias_kernel<<<g, 256, 0, stream>>>(hcat, nullptr, 2 * HDIM, fc_hid_W, 2 * HDIM,
                                                fc_hid_b, dst, HDIM, NBATCH, HDIM, 2 * HDIM);
        gemm_bias_kernel<<<g, 256, 0, stream>>>(ccat, nullptr, 2 * HDIM, fc_cell_W, 2 * HDIM,
                                                fc_cell_b, dst + HS, HDIM, NBATCH, HDIM, 2 * HDIM);
    }

    // decoder embedding contribution (reuses Xf buffer — safe: encoder done)
    {
        dim3 g(G4H / 128, (TSTEPS * NBATCH + 127) / 128);
        gemm_bias_kernel<<<g, 256, 0, stream>>>(dec_emb, target, EDIM, dec_Wih + 2 * HDIM,
                                                LDW_DEC, dec_b, Xd, G4H,
                                                TSTEPS * NBATCH, G4H, EDIM);
    }

    // persistent decoder (49 steps, 1 launch)
    {
        DecP dp;
        dp.Xd = Xd; dp.Wih = dec_Wih; dp.Whh = dec_Whh; dp.ee = ee;
        dp.WhE = energy_W; dp.out_f = out_f; dp.out_b = out_b;
        dp.dst = dst; dp.ctx = ctx; dp.Hs = Hs; dp.bar = bars + 1;
        void* args[] = { &dp };
        hipLaunchCooperativeKernel((const void*)dec_persist, dim3(256), dim3(256),
                                   args, 0, stream);
    }

    // deferred output projection: preds = Hs @ fc_W.T + fc_b  -> out[1:]
    {
        dim3 g((VTGT + 127) / 128, (TSTEPS * NBATCH + 127) / 128);
        gemm_bias_kernel<<<g, 256, 0, stream>>>(Hs, nullptr, HDIM, fc_W, HDIM, fc_b,
                                                out + (size_t)NBATCH * VTGT, VTGT,
                                                TSTEPS * NBATCH, VTGT, HDIM);
    }
}